// Round 6
// baseline (268.413 us; speedup 1.0000x reference)
//
#include <hip/hip_runtime.h>
#include <math.h>

#define NN 4096
#define LN_EPS 1e-5f
#define EPS 1e-8f

typedef unsigned short ushortT;
typedef unsigned int uintT;
typedef __attribute__((ext_vector_type(8))) short short8;
typedef __attribute__((ext_vector_type(4))) float f32x4;
typedef __attribute__((ext_vector_type(2))) float f32x2;
typedef __attribute__((ext_vector_type(4))) unsigned short us4;

// workspace offsets (in floats)
#define OFF_XN    0L         // xn bf16 A-frags [b][c][frag8][lane64][j8] = 8388608 f
#define OFF_QU    8388608L   // q' packed uint [it=3][b][kb][lane64][j2=4] = 98304
#define OFF_AP    8486912L   // accPart [it=3][b][e=8][512] f32 = 786432
#define OFF_CP    9273344L   // colPart [it=3][b][e=8][8] f32 = 12288
#define OFF_SLOTS 9285632L   // slotsV [it=3][b][k][d] f32 = 98304
#define OFF_WIHT  9383936L   // w_ih^T [64][192] = 12288
#define OFF_WHHT  9396224L   // w_hh^T [64][192] = 12288
#define OFF_W1T   9408512L   // mlp_w1^T [64][128] = 8192
#define OFF_W2T   9416704L   // mlp_w2^T [128][64] = 8192
#define OFF_WQT   9424896L   // Wq^T [64][64] = 4096
#define OFF_WVT   9428992L   // Wv^T [f][d] = 4096
#define OFF_CNT   9433088L   // uint cnt[3*64]
#define OFF_RDY   9433280L   // uint ready[64]

__device__ __forceinline__ float wredsum(float v) {
#pragma unroll
  for (int off = 32; off > 0; off >>= 1) v += __shfl_xor(v, off);
  return v;
}

__device__ __forceinline__ ushortT f2bf(float f) {
  uintT b = __float_as_uint(f);
  b += 0x7fff + ((b >> 16) & 1);          // RNE
  return (ushortT)(b >> 16);
}

__device__ __forceinline__ uintT pack2bf(float lo, float hi) {
  return (uintT)f2bf(lo) | ((uintT)f2bf(hi) << 16);
}

// coherent (memory-side) stores: bypass/through L2 so cross-XCD readers that
// first-touch the line observe the data. No RMW — full-width burst writes.
__device__ __forceinline__ void store2_coh(float* p, f32x2 v) {
  asm volatile("global_store_dwordx2 %0, %1, off sc0 sc1" :: "v"(p), "v"(v) : "memory");
}
__device__ __forceinline__ void store1f_coh(float* p, float v) {
  asm volatile("global_store_dword %0, %1, off sc0 sc1" :: "v"(p), "v"(v) : "memory");
}
__device__ __forceinline__ void store1u_coh(uintT* p, uintT v) {
  asm volatile("global_store_dword %0, %1, off sc0 sc1" :: "v"(p), "v"(v) : "memory");
}
// coherent load (bypasses stale L1/L2) — used only for the ready-flag spin.
__device__ __forceinline__ uintT load1u_coh(const uintT* p) {
  uintT r;
  asm volatile("global_load_dword %0, %1, off sc0 sc1\n\t"
               "s_waitcnt vmcnt(0)" : "=v"(r) : "v"(p) : "memory");
  return r;
}
__device__ __forceinline__ void drain_vm() {
  asm volatile("s_waitcnt vmcnt(0)" ::: "memory");
}

// ---------------------------------------------------------------------------
// K0: weight prep + zero cnt/ready counters.
__global__ __launch_bounds__(256) void k_prep(
    const float* __restrict__ w_ih, const float* __restrict__ w_hh,
    const float* __restrict__ w1, const float* __restrict__ w2,
    const float* __restrict__ Wq, const float* __restrict__ Wv,
    float* __restrict__ wihT, float* __restrict__ whhT,
    float* __restrict__ w1T, float* __restrict__ w2T, float* __restrict__ wqT,
    float* __restrict__ wvT, uintT* __restrict__ cnt, uintT* __restrict__ ready)
{
  int idx = blockIdx.x * 256 + threadIdx.x;
  if (idx < 12288) {
    int j = idx >> 6, f = idx & 63;
    wihT[f * 192 + j] = w_ih[idx];
  } else if (idx < 24576) {
    int i = idx - 12288; int j = i >> 6, f = i & 63;
    whhT[f * 192 + j] = w_hh[i];
  } else if (idx < 32768) {
    int i = idx - 24576; int j = i >> 6, f = i & 63;
    w1T[f * 128 + j] = w1[i];
  } else if (idx < 40960) {
    int i = idx - 32768; int d = i >> 7, j = i & 127;
    w2T[j * 64 + d] = w2[i];
  } else if (idx < 45056) {
    int i = idx - 40960; int e = i >> 6, d = i & 63;
    wqT[d * 64 + e] = Wq[i];
  } else if (idx < 49152) {
    int i = idx - 45056; int d = i >> 6, f = i & 63;
    wvT[f * 64 + d] = Wv[i];         // wvT[f][d] = Wv[d][f]
  } else if (idx < 49344) {
    cnt[idx - 49152] = 0u;
  } else if (idx < 49408) {
    ready[idx - 49344] = 0u;
  }
}

// ---------------------------------------------------------------------------
// K1: LayerNorm -> xn bf16 A-frags (blocks 0..4095); slot init + q'[0] packed
// (4096..4223). Also zeroes the dead q' columns (8..15) for all 3 iteration
// versions. No acc zeroing needed anymore (partials are overwrite-only).
__global__ __launch_bounds__(256) void k_ln_init(
    const float* __restrict__ inp,
    const float* __restrict__ g, const float* __restrict__ bbv,
    ushortT* __restrict__ xnG,
    const float* __restrict__ noise, const float* __restrict__ smu,
    const float* __restrict__ slsig, const float* __restrict__ wqT,
    const float* __restrict__ Wk,
    const float* __restrict__ g_sl, const float* __restrict__ b_sl,
    float* __restrict__ slotsV, uintT* __restrict__ qU)
{
  __shared__ __align__(16) ushortT xnF[4096];   // [frag8][lane64][j8]
  const int tid = threadIdx.x;
  const int lane = tid & 63;
  const int wave = tid >> 6;

  if (blockIdx.x >= 4096) {
    // ---- slot init branch ----
    const int bi = blockIdx.x - 4096;
    const int row = bi * 4 + wave;               // 0..511
    const int b = row >> 3, ks = row & 7;
    float* SI = (float*)&xnF[0];                 // 2048 floats; per-wave 512
    float* Sw = SI + (wave << 9);

    float s0 = fmaf(expf(slsig[lane]), noise[row * 64 + lane], smu[lane]);
    slotsV[row * 64 + lane] = s0;                // slotsV[0]

    float mu = wredsum(s0) * (1.f / 64.f);
    float dx = s0 - mu;
    float var = wredsum(dx * dx) * (1.f / 64.f);
    float sn = dx * rsqrtf(var + LN_EPS) * g_sl[lane] + b_sl[lane];
    Sw[lane] = sn;
    float qe = 0.f;
#pragma unroll 16
    for (int d = 0; d < 64; ++d) qe = fmaf(Sw[d], wqT[d * 64 + lane], qe);
    Sw[64 + lane] = qe;
    float qp = 0.f;
#pragma unroll 16
    for (int e = 0; e < 64; ++e) qp = fmaf(Sw[64 + e], Wk[e * 64 + lane], qp);
    Sw[128 + lane] = qp * 0.125f;     // scaled q' at index f=lane
    if (lane < 32) {
      const int kb = lane >> 4, lrow = (lane >> 2) & 3, j2 = lane & 3;
      const int fA = kb * 32 + lrow * 8 + 2 * j2;
      uintT u = pack2bf(Sw[128 + fA], Sw[128 + fA + 1]);
      qU[((b * 2 + kb) * 64 + lrow * 16 + ks) * 4 + j2] = u;     // qU[0] real
#pragma unroll
      for (int v = 0; v < 3; ++v)      // dead cols (8..15) zero, all versions
        qU[v * 32768 + ((b * 2 + kb) * 64 + lrow * 16 + 8 + ks) * 4 + j2] = 0u;
    }
    return;
  }

  // ---- LN branch ----
  const int l15 = lane & 15, q = lane >> 4;
  const int tile = blockIdx.x;
  const int b = tile >> 6;
  const int c = tile & 63;
  const int n0 = c << 6;
  const float* rowbase = inp + (((long)b * NN + n0) << 6);
  const float4 g4 = *(const float4*)&g[l15 << 2];
  const float4 b4 = *(const float4*)&bbv[l15 << 2];

#pragma unroll
  for (int i = 0; i < 4; ++i) {
    const int row = (wave << 4) + (i << 2) + q;
    float4 x = *(const float4*)&rowbase[(row << 6) + (l15 << 2)];
    float s = x.x + x.y + x.z + x.w;
    s += __shfl_xor(s, 1); s += __shfl_xor(s, 2);
    s += __shfl_xor(s, 4); s += __shfl_xor(s, 8);
    const float mu = s * (1.f / 64.f);
    float4 dx = {x.x - mu, x.y - mu, x.z - mu, x.w - mu};
    float ss = dx.x * dx.x + dx.y * dx.y + dx.z * dx.z + dx.w * dx.w;
    ss += __shfl_xor(ss, 1); ss += __shfl_xor(ss, 2);
    ss += __shfl_xor(ss, 4); ss += __shfl_xor(ss, 8);
    const float rs = rsqrtf(ss * (1.f / 64.f) + LN_EPS);
    us4 p = {f2bf(dx.x * rs * g4.x + b4.x), f2bf(dx.y * rs * g4.y + b4.y),
             f2bf(dx.z * rs * g4.z + b4.z), f2bf(dx.w * rs * g4.w + b4.w)};
    *(us4*)&xnF[((((wave << 1) + (l15 >> 3)) << 6) + (((l15 & 7) >> 1) << 4)
                 + (row & 15)) * 8 + ((l15 & 1) << 2)] = p;
  }
  __syncthreads();

  ushortT* dst = xnG + ((long)(b * 64 + c) << 12);
  short8 v0 = *(const short8*)&xnF[tid << 4];
  short8 v1 = *(const short8*)&xnF[(tid << 4) + 8];
  *(short8*)&dst[tid << 4] = v0;
  *(short8*)&dst[(tid << 4) + 8] = v1;
}

// ---------------------------------------------------------------------------
// K2: persistent fused attention, RMW-free protocol (R5 post-mortem: the
// ~50us/iter floor tracked the 1.3M fabric atomic RMWs/iter, not fetch).
//   - All cross-block buffers versioned by iteration -> every read is a
//     first-touch plain load (no stale-line hazard, full cache-line bursts).
//   - Writers publish with sc0sc1 coherent stores (memory-side, no RMW).
//   - Remaining RMWs: cnt (1/block/iter) + ready (1/batch/iter). Spin uses a
//     coherent LOAD, not an RMW.
//   - In-LDS transpose hoisted out of the iteration loop (vB regs persist).
__global__ __launch_bounds__(256, 2) void k_attn(
    const ushortT* __restrict__ xnG, uintT* __restrict__ qU,
    float* __restrict__ accPart, float* __restrict__ colPart,
    uintT* __restrict__ cnt, uintT* __restrict__ ready,
    float* __restrict__ slotsV,
    const float* __restrict__ wihT, const float* __restrict__ whhT,
    const float* __restrict__ w1T, const float* __restrict__ w2T,
    const float* __restrict__ wqT, const float* __restrict__ Wk,
    const float* __restrict__ wvT,
    const float* __restrict__ b_ih, const float* __restrict__ b_hh,
    const float* __restrict__ mb1, const float* __restrict__ mb2,
    const float* __restrict__ g_ml, const float* __restrict__ b_ml,
    const float* __restrict__ g_sl, const float* __restrict__ b_sl,
    float* __restrict__ dout)
{
  __shared__ __align__(16) ushortT XW[4][4096];
  __shared__ int lastFlag;
  const int tid = threadIdx.x;
  const int lane = tid & 63;
  const int wave = tid >> 6;
  const int l15 = lane & 15, q = lane >> 4;
  const int b = blockIdx.x >> 3;
  const int e = blockIdx.x & 7;        // eighth of the batch

  ushortT* xT = &XW[wave][0];

  const ushortT* pc0 = xnG + ((long)(b * 64 + (e << 3) + wave) << 12);
  const ushortT* pc1 = pc0 + (4L << 12);

  // load both chunks' A-frags ONCE; held in VGPRs for the whole kernel
  short8 kA0[4][2], kA1[4][2];
#pragma unroll
  for (int mt = 0; mt < 4; ++mt)
#pragma unroll
    for (int kb = 0; kb < 2; ++kb) {
      kA0[mt][kb] = *(const short8*)&pc0[((mt * 2 + kb) * 64 + lane) << 3];
      kA1[mt][kb] = *(const short8*)&pc1[((mt * 2 + kb) * 64 + lane) << 3];
    }

  // hoisted in-LDS transpose (iteration-invariant): A-frags -> PV B-frags
  short8 vB0[4][2], vB1[4][2];
  {
    const int h = ((lane >> 5) << 2) | (((lane & 15) >> 3) << 1) | ((lane >> 4) & 1);
    const int jp = lane & 7;
    const int lpA = (((lane >> 4) & 1) << 3) + (((lane & 15) >> 3) << 4);
#pragma unroll
    for (int ch = 0; ch < 2; ++ch) {
#pragma unroll
      for (int mt = 0; mt < 4; ++mt)
#pragma unroll
        for (int kb = 0; kb < 2; ++kb) {
          const int fb = (kb * 4 + ((lane >> 5) << 1) + (mt >> 1)) << 9;
          const int lm = lpA + ((mt & 1) << 5);
          const short8 src8 = ch ? kA1[mt][kb] : kA0[mt][kb];
          const ushortT* src = (const ushortT*)&src8;
#pragma unroll
          for (int j = 0; j < 8; ++j)
            xT[fb + (((lm + j) ^ h) << 3) + jp] = src[j];
        }
#pragma unroll
      for (int nt = 0; nt < 4; ++nt)
#pragma unroll
        for (int ks = 0; ks < 2; ++ks) {
          const int frag = nt * 2 + ks;
          const int hr = ((nt & 1) << 2) | (((lane >> 4) & 1) << 1) | ((lane >> 3) & 1);
          short8 v = *(const short8*)&xT[(frag << 9) + ((lane ^ hr) << 3)];
          if (ch) vB1[nt][ks] = v; else vB0[nt][ks] = v;
        }
    }
  }

  for (int it = 0; it < 3; ++it) {
    if (it > 0) {
      if (tid == 0) {
        while (load1u_coh(&ready[b]) < (uintT)it) __builtin_amdgcn_s_sleep(2);
      }
      __syncthreads();
    }

    // q' for this iteration: versioned buffer -> first-touch plain loads
    const uintT* qIt = qU + it * 32768;
    short8 qB[2];
#pragma unroll
    for (int kb = 0; kb < 2; ++kb)
      qB[kb] = *(const short8*)&qIt[((b * 2 + kb) * 64 + lane) * 4];

    f32x4 accP[4];
#pragma unroll
    for (int nt = 0; nt < 4; ++nt) accP[nt] = (f32x4){0.f, 0.f, 0.f, 0.f};
    float csum = 0.f;

#pragma unroll
    for (int ch = 0; ch < 2; ++ch) {
      f32x4 accL[4];
#pragma unroll
      for (int mt = 0; mt < 4; ++mt) {
        const short8 a0 = ch ? kA1[mt][0] : kA0[mt][0];
        const short8 a1 = ch ? kA1[mt][1] : kA0[mt][1];
        accL[mt] = (f32x4){0.f, 0.f, 0.f, 0.f};
        accL[mt] = __builtin_amdgcn_mfma_f32_16x16x32_bf16(a0, qB[0], accL[mt], 0, 0, 0);
        accL[mt] = __builtin_amdgcn_mfma_f32_16x16x32_bf16(a1, qB[1], accL[mt], 0, 0, 0);
      }

      // softmax over slots (cols 8..15 benign: q' cols zeroed)
      ushortT* attnF = &XW[wave][0];
#pragma unroll
      for (int mt = 0; mt < 4; ++mt) {
        float av[4];
#pragma unroll
        for (int r = 0; r < 4; ++r) {
          float lv = accL[mt][r];
          float mx = lv;
          mx = fmaxf(mx, __shfl_xor(mx, 1));
          mx = fmaxf(mx, __shfl_xor(mx, 2));
          mx = fmaxf(mx, __shfl_xor(mx, 4));
          float ev = __expf(lv - mx);
          float sv = ev;
          sv += __shfl_xor(sv, 1); sv += __shfl_xor(sv, 2); sv += __shfl_xor(sv, 4);
          float a = ev * (1.f / sv) + EPS;
          av[r] = a;
          csum += a;
        }
        us4 p = {f2bf(av[0]), f2bf(av[1]), f2bf(av[2]), f2bf(av[3])};
        *(us4*)&attnF[((((mt >> 1) << 6) + (((mt & 1) * 2 + (q >> 1)) << 4)
                        + l15) << 3) + ((q & 1) << 2)] = p;
      }

      short8 pA0 = *(const short8*)&attnF[(0 * 64 + lane) << 3];
      short8 pA1 = *(const short8*)&attnF[(1 * 64 + lane) << 3];

#pragma unroll
      for (int nt = 0; nt < 4; ++nt) {
        const short8 v0 = ch ? vB1[nt][0] : vB0[nt][0];
        const short8 v1 = ch ? vB1[nt][1] : vB0[nt][1];
        accP[nt] = __builtin_amdgcn_mfma_f32_16x16x32_bf16(pA0, v0, accP[nt], 0, 0, 0);
        accP[nt] = __builtin_amdgcn_mfma_f32_16x16x32_bf16(pA1, v1, accP[nt], 0, 0, 0);
      }
    }

    csum += __shfl_xor(csum, 16);
    csum += __shfl_xor(csum, 32);

    // cross-wave reduce in LDS, then ONE coherent store of the block partial
    float* accLw = (float*)&XW[wave][1024];
    float* colLw = (float*)&XW[wave][2048];
    if (q < 2) {
#pragma unroll
      for (int nt = 0; nt < 4; ++nt)
#pragma unroll
        for (int r = 0; r < 4; ++r)
          accLw[(q * 4 + r) * 64 + nt * 16 + l15] = accP[nt][r];
    }
    if (q == 0 && l15 < 8) colLw[l15] = csum;
    __syncthreads();

    float* apIt = accPart + ((long)(it * 64 + b) * 8 + e) * 512;
    float* cpIt = colPart + ((long)(it * 64 + b) * 8 + e) * 8;
    {
      const int o = tid * 2;
      f32x2 s;
#pragma unroll
      for (int r = 0; r < 2; ++r) {
        const int oo = o + r;
        s[r] = *((float*)&XW[0][1024] + oo) + *((float*)&XW[1][1024] + oo)
             + *((float*)&XW[2][1024] + oo) + *((float*)&XW[3][1024] + oo);
      }
      store2_coh(&apIt[o], s);
    }
    if (tid < 8) {
      float s = *((float*)&XW[0][2048] + tid) + *((float*)&XW[1][2048] + tid)
              + *((float*)&XW[2][2048] + tid) + *((float*)&XW[3][2048] + tid);
      store1f_coh(&cpIt[tid], s);
    }

    // completion: drain our stores, then last block of (it,b) runs the update
    drain_vm();
    __syncthreads();
    if (tid == 0) lastFlag = (atomicAdd(&cnt[it * 64 + b], 1u) == 7u);
    __syncthreads();

    if (lastFlag) {
      const int ks0 = wave, ks1 = wave + 4;
      const int row0 = b * 8 + ks0, row1 = b * 8 + ks1;
      const float* apB = accPart + (long)(it * 64 + b) * 8 * 512;
      const float* cpB = colPart + (long)(it * 64 + b) * 8 * 8;
      const float* slIt = slotsV + it * 32768;

      float csv0 = 0.f, csv1 = 0.f, t0 = 0.f, t1 = 0.f;
#pragma unroll
      for (int ee = 0; ee < 8; ++ee) {
        csv0 += cpB[ee * 8 + ks0];
        csv1 += cpB[ee * 8 + ks1];
        t0 += apB[ee * 512 + ks0 * 64 + lane];
        t1 += apB[ee * 512 + ks1 * 64 + lane];
      }
      t0 /= csv0; t1 /= csv1;
      const float h0 = slIt[row0 * 64 + lane];
      const float h1 = slIt[row1 * 64 + lane];

      float* S = (float*)&XW[wave][0];

      // updates = (t/csum) @ Wv^T  (f32 weights)
      S[256 + lane] = t0; S[320 + lane] = t1;
      float u0 = 0.f, u1 = 0.f;
#pragma unroll 4
      for (int f = 0; f < 64; ++f) {
        const float wv = wvT[f * 64 + lane];
        u0 = fmaf(S[256 + f], wv, u0);
        u1 = fmaf(S[320 + f], wv, u1);
      }

      S[lane] = u0; S[64 + lane] = u1; S[128 + lane] = h0; S[192 + lane] = h1;

      float gir0 = b_ih[lane], giz0 = b_ih[64 + lane], gin0 = b_ih[128 + lane];
      float ghr0 = b_hh[lane], ghz0 = b_hh[64 + lane], ghn0 = b_hh[128 + lane];
      float gir1 = gir0, giz1 = giz0, gin1 = gin0;
      float ghr1 = ghr0, ghz1 = ghz0, ghn1 = ghn0;
#pragma unroll 4
      for (int f = 0; f < 64; ++f) {
        const float wr = wihT[f * 192 + lane], wz = wihT[f * 192 + 64 + lane],
                    wn = wihT[f * 192 + 128 + lane];
        const float vr = whhT[f * 192 + lane], vz = whhT[f * 192 + 64 + lane],
                    vn = whhT[f * 192 + 128 + lane];
        const float a0 = S[f], a1 = S[64 + f], c0 = S[128 + f], c1 = S[192 + f];
        gir0 = fmaf(a0, wr, gir0); gir1 = fmaf(a1, wr, gir1);
        giz0 = fmaf(a0, wz, giz0); giz1 = fmaf(a1, wz, giz1);
        gin0 = fmaf(a0, wn, gin0); gin1 = fmaf(a1, wn, gin1);
        ghr0 = fmaf(c0, vr, ghr0); ghr1 = fmaf(c1, vr, ghr1);
        ghz0 = fmaf(c0, vz, ghz0); ghz1 = fmaf(c1, vz, ghz1);
        ghn0 = fmaf(c0, vn, ghn0); ghn1 = fmaf(c1, vn, ghn1);
      }
      const float r0 = 1.f / (1.f + expf(-(gir0 + ghr0)));
      const float z0 = 1.f / (1.f + expf(-(giz0 + ghz0)));
      const float n0 = tanhf(fmaf(r0, ghn0, gin0));
      const float hn0 = (1.f - z0) * n0 + z0 * h0;
      const float r1 = 1.f / (1.f + expf(-(gir1 + ghr1)));
      const float z1 = 1.f / (1.f + expf(-(giz1 + ghz1)));
      const float n1 = tanhf(fmaf(r1, ghn1, gin1));
      const float hn1 = (1.f - z1) * n1 + z1 * h1;

      float mu0 = wredsum(hn0) * (1.f / 64.f);
      float dx0 = hn0 - mu0;
      float va0 = wredsum(dx0 * dx0) * (1.f / 64.f);
      const float ln0 = dx0 * rsqrtf(va0 + LN_EPS) * g_ml[lane] + b_ml[lane];
      float mu1 = wredsum(hn1) * (1.f / 64.f);
      float dx1 = hn1 - mu1;
      float va1 = wredsum(dx1 * dx1) * (1.f / 64.f);
      const float ln1 = dx1 * rsqrtf(va1 + LN_EPS) * g_ml[lane] + b_ml[lane];
      S[256 + lane] = ln0; S[320 + lane] = ln1;

      float h1a0 = mb1[lane], h1b0 = mb1[64 + lane];
      float h1a1 = h1a0, h1b1 = h1b0;
#pragma unroll 4
      for (int f = 0; f < 64; ++f) {
        const float wa = w1T[f * 128 + lane], wb = w1T[f * 128 + 64 + lane];
        const float l0 = S[256 + f], l1 = S[320 + f];
        h1a0 = fmaf(l0, wa, h1a0); h1a1 = fmaf(l1, wa, h1a1);
        h1b0 = fmaf(l0, wb, h1b0); h1b1 = fmaf(l1, wb, h1b1);
      }
      h1a0 = fmaxf(h1a0, 0.f); h1b0 = fmaxf(h1b0, 0.f);
      h1a1 = fmaxf(h1a1, 0.f); h1b1 = fmaxf(h1b1, 0.f);
      S[lane] = h1a0; S[64 + lane] = h1b0;
      S[128 + lane] = h1a1; S[192 + lane] = h1b1;

      float o0 = mb2[lane], o1 = mb2[lane];
#pragma unroll 4
      for (int j = 0; j < 128; ++j) {
        const float w2v = w2T[j * 64 + lane];
        o0 = fmaf(S[j], w2v, o0);
        o1 = fmaf(S[128 + j], w2v, o1);
      }
      const float sn0 = hn0 + o0;
      const float sn1 = hn1 + o1;

      if (it == 2) {
        dout[row0 * 64 + lane] = sn0;
        dout[row1 * 64 + lane] = sn1;
      } else {
        // publish next-iteration slots (coherent stores, versioned buffer)
        float* slN = slotsV + (it + 1) * 32768;
        store1f_coh(&slN[row0 * 64 + lane], sn0);
        store1f_coh(&slN[row1 * 64 + lane], sn1);

        // next-iteration q' = (LN_slots(snew) @ Wq^T) @ Wk * D^-0.5
        float m20 = wredsum(sn0) * (1.f / 64.f);
        float d20 = sn0 - m20;
        float v20 = wredsum(d20 * d20) * (1.f / 64.f);
        const float sq0 = d20 * rsqrtf(v20 + LN_EPS) * g_sl[lane] + b_sl[lane];
        float m21 = wredsum(sn1) * (1.f / 64.f);
        float d21 = sn1 - m21;
        float v21 = wredsum(d21 * d21) * (1.f / 64.f);
        const float sq1 = d21 * rsqrtf(v21 + LN_EPS) * g_sl[lane] + b_sl[lane];
        S[256 + lane] = sq0; S[320 + lane] = sq1;
        float qe0 = 0.f, qe1 = 0.f;
#pragma unroll 8
        for (int d = 0; d < 64; ++d) {
          const float wq = wqT[d * 64 + lane];
          qe0 = fmaf(S[256 + d], wq, qe0);
          qe1 = fmaf(S[320 + d], wq, qe1);
        }
        S[256 + lane] = qe0; S[320 + lane] = qe1;
        float qp0 = 0.f, qp1 = 0.f;
#pragma unroll 8
        for (int e2 = 0; e2 < 64; ++e2) {
          const float wk = Wk[e2 * 64 + lane];
          qp0 = fmaf(S[256 + e2], wk, qp0);
          qp1 = fmaf(S[320 + e2], wk, qp1);
        }
        S[384 + lane] = qp0 * 0.125f;
        S[448 + lane] = qp1 * 0.125f;
        {
          uintT* qN = qU + (it + 1) * 32768;
          const int rr = lane >> 5, L5 = lane & 31;
          const int kb = L5 >> 4, lrow = (L5 >> 2) & 3, j2 = L5 & 3;
          const int fA = kb * 32 + lrow * 8 + 2 * j2;
          const int ksr = rr ? ks1 : ks0;
          uintT u = pack2bf(S[384 + rr * 64 + fA], S[384 + rr * 64 + fA + 1]);
          store1u_coh(&qN[((b * 2 + kb) * 64 + lrow * 16 + ksr) * 4 + j2], u);
        }
        // drain publish stores (per-thread), barrier, then raise the flag:
        // flag visibility implies data visibility (stores are memory-side).
        drain_vm();
        __syncthreads();
        if (tid == 0) atomicAdd(&ready[b], 1u);
      }
    }
  }
}

// ---------------------------------------------------------------------------
extern "C" void kernel_launch(void* const* d_in, const int* in_sizes, int n_in,
                              void* d_out, int out_size, void* d_ws, size_t ws_size,
                              hipStream_t stream) {
  const float* inp   = (const float*)d_in[0];
  const float* noise = (const float*)d_in[1];
  const float* smu   = (const float*)d_in[2];
  const float* slsig = (const float*)d_in[3];
  const float* Wq    = (const float*)d_in[4];
  const float* Wk    = (const float*)d_in[5];
  const float* Wv    = (const float*)d_in[6];
  const float* w_ih  = (const float*)d_in[7];
  const float* w_hh  = (const float*)d_in[8];
  const float* b_ih  = (const float*)d_in[9];
  const float* b_hh  = (const float*)d_in[10];
  const float* w1    = (const float*)d_in[11];
  const float* b1    = (const float*)d_in[12];
  const float* w2    = (const float*)d_in[13];
  const float* b2    = (const float*)d_in[14];
  const float* g_in  = (const float*)d_in[15];
  const float* bi_in = (const float*)d_in[16];
  const float* g_sl  = (const float*)d_in[17];
  const float* bi_sl = (const float*)d_in[18];
  const float* g_ml  = (const float*)d_in[19];
  const float* bi_ml = (const float*)d_in[20];

  float* ws      = (float*)d_ws;
  ushortT* xnG   = (ushortT*)(ws + OFF_XN);
  uintT* qU      = (uintT*)(ws + OFF_QU);
  float* ap      = ws + OFF_AP;
  float* cp      = ws + OFF_CP;
  float* sl      = ws + OFF_SLOTS;
  float* wihT    = ws + OFF_WIHT;
  float* whhT    = ws + OFF_WHHT;
  float* w1T     = ws + OFF_W1T;
  float* w2T     = ws + OFF_W2T;
  float* wqT     = ws + OFF_WQT;
  float* wvT     = ws + OFF_WVT;
  uintT* cnt     = (uintT*)(ws + OFF_CNT);
  uintT* rdy     = (uintT*)(ws + OFF_RDY);

  k_prep<<<194, 256, 0, stream>>>(w_ih, w_hh, w1, w2, Wq, Wv,
                                  wihT, whhT, w1T, w2T, wqT, wvT, cnt, rdy);
  k_ln_init<<<4224, 256, 0, stream>>>(inp, g_in, bi_in, xnG,
                                      noise, smu, slsig, wqT, Wk, g_sl, bi_sl,
                                      sl, qU);
  k_attn<<<512, 256, 0, stream>>>(xnG, qU, ap, cp, cnt, rdy, sl,
                                  wihT, whhT, w1T, w2T, wqT, Wk, wvT,
                                  b_ih, b_hh, b1, b2, g_ml, bi_ml, g_sl, bi_sl,
                                  (float*)d_out);
}

// Round 7
// 244.830 us; speedup vs baseline: 1.0963x; 1.0963x over previous
//
#include <hip/hip_runtime.h>
#include <math.h>

#define NN 4096
#define LN_EPS 1e-5f
#define EPS 1e-8f

typedef unsigned short ushortT;
typedef unsigned int uintT;
typedef __attribute__((ext_vector_type(8))) short short8;
typedef __attribute__((ext_vector_type(4))) float f32x4;
typedef __attribute__((ext_vector_type(2))) float f32x2;
typedef __attribute__((ext_vector_type(4))) unsigned short us4;

// workspace offsets (floats) — xn buffer ELIMINATED (LN fused into k_attn).
// Total ~4.2 MB.
#define OFF_QU    0L         // q' packed uint [it3][b][kb][lane64][j2=4] = 98304
#define OFF_AP    98304L     // accPart [it3][b][e8][512] f32 = 786432
#define OFF_CP    884736L    // colPart [it3][b][e8][8] f32 = 12288
#define OFF_SLOTS 897024L    // slotsV [it3][b][k][d] f32 = 98304
#define OFF_WIHT  995328L    // w_ih^T [64][192] = 12288
#define OFF_WHHT  1007616L   // w_hh^T [64][192] = 12288
#define OFF_W1T   1019904L   // mlp_w1^T [64][128] = 8192
#define OFF_W2T   1028096L   // mlp_w2^T [128][64] = 8192
#define OFF_WQT   1036288L   // Wq^T [64][64] = 4096
#define OFF_WVT   1040384L   // Wv^T [f][d] = 4096
#define OFF_CNT   1044480L   // uint cnt[3*64]
#define OFF_RDY   1044672L   // uint ready[64]

__device__ __forceinline__ float wredsum(float v) {
#pragma unroll
  for (int off = 32; off > 0; off >>= 1) v += __shfl_xor(v, off);
  return v;
}

__device__ __forceinline__ ushortT f2bf(float f) {
  uintT b = __float_as_uint(f);
  b += 0x7fff + ((b >> 16) & 1);          // RNE
  return (ushortT)(b >> 16);
}

__device__ __forceinline__ uintT pack2bf(float lo, float hi) {
  return (uintT)f2bf(lo) | ((uintT)f2bf(hi) << 16);
}

// coherent (memory-side) stores/loads for the cross-block protocol (no RMW).
__device__ __forceinline__ void store2_coh(float* p, f32x2 v) {
  asm volatile("global_store_dwordx2 %0, %1, off sc0 sc1" :: "v"(p), "v"(v) : "memory");
}
__device__ __forceinline__ void store1f_coh(float* p, float v) {
  asm volatile("global_store_dword %0, %1, off sc0 sc1" :: "v"(p), "v"(v) : "memory");
}
__device__ __forceinline__ void store1u_coh(uintT* p, uintT v) {
  asm volatile("global_store_dword %0, %1, off sc0 sc1" :: "v"(p), "v"(v) : "memory");
}
__device__ __forceinline__ uintT load1u_coh(const uintT* p) {
  uintT r;
  asm volatile("global_load_dword %0, %1, off sc0 sc1\n\t"
               "s_waitcnt vmcnt(0)" : "=v"(r) : "v"(p) : "memory");
  return r;
}
__device__ __forceinline__ void drain_vm() {
  asm volatile("s_waitcnt vmcnt(0)" ::: "memory");
}
__device__ __forceinline__ void wait_lds() {
  asm volatile("s_waitcnt lgkmcnt(0)" ::: "memory");
}

// ---------------------------------------------------------------------------
// K0: weight prep + cnt/ready zero (blocks 0..193) PLUS slot init + q'[0]
// (blocks 194..321). Init uses RAW Wq/Wk (wqT[d*64+e] == Wq[e*64+d], same fma
// order as before -> bit-identical), so there is no intra-kernel dependency.
__global__ __launch_bounds__(256) void k_prep(
    const float* __restrict__ w_ih, const float* __restrict__ w_hh,
    const float* __restrict__ w1, const float* __restrict__ w2,
    const float* __restrict__ Wq, const float* __restrict__ Wv,
    const float* __restrict__ Wk,
    const float* __restrict__ noise, const float* __restrict__ smu,
    const float* __restrict__ slsig,
    const float* __restrict__ g_sl, const float* __restrict__ b_sl,
    float* __restrict__ wihT, float* __restrict__ whhT,
    float* __restrict__ w1T, float* __restrict__ w2T, float* __restrict__ wqT,
    float* __restrict__ wvT, float* __restrict__ slotsV, uintT* __restrict__ qU,
    uintT* __restrict__ cnt, uintT* __restrict__ ready)
{
  const int tid = threadIdx.x;
  if (blockIdx.x >= 194) {
    // ---- slot init + q'[0] branch ----
    __shared__ float SI[4][192];
    const int lane = tid & 63, wave = tid >> 6;
    const int bi = blockIdx.x - 194;
    const int row = bi * 4 + wave;               // 0..511
    const int b = row >> 3, ks = row & 7;
    float* Sw = SI[wave];

    float s0 = fmaf(expf(slsig[lane]), noise[row * 64 + lane], smu[lane]);
    slotsV[row * 64 + lane] = s0;                // slotsV[0]

    float mu = wredsum(s0) * (1.f / 64.f);
    float dx = s0 - mu;
    float var = wredsum(dx * dx) * (1.f / 64.f);
    float sn = dx * rsqrtf(var + LN_EPS) * g_sl[lane] + b_sl[lane];
    Sw[lane] = sn;
    float qe = 0.f;
#pragma unroll 16
    for (int d = 0; d < 64; ++d) qe = fmaf(Sw[d], Wq[lane * 64 + d], qe);
    Sw[64 + lane] = qe;
    float qp = 0.f;
#pragma unroll 16
    for (int e = 0; e < 64; ++e) qp = fmaf(Sw[64 + e], Wk[e * 64 + lane], qp);
    Sw[128 + lane] = qp * 0.125f;
    if (lane < 32) {
      const int kb = lane >> 4, lrow = (lane >> 2) & 3, j2 = lane & 3;
      const int fA = kb * 32 + lrow * 8 + 2 * j2;
      uintT u = pack2bf(Sw[128 + fA], Sw[128 + fA + 1]);
      qU[((b * 2 + kb) * 64 + lrow * 16 + ks) * 4 + j2] = u;     // qU[0]
#pragma unroll
      for (int v = 0; v < 3; ++v)      // dead cols (8..15) zero, all versions
        qU[v * 32768 + ((b * 2 + kb) * 64 + lrow * 16 + 8 + ks) * 4 + j2] = 0u;
    }
    return;
  }

  int idx = blockIdx.x * 256 + tid;
  if (idx < 12288) {
    int j = idx >> 6, f = idx & 63;
    wihT[f * 192 + j] = w_ih[idx];
  } else if (idx < 24576) {
    int i = idx - 12288; int j = i >> 6, f = i & 63;
    whhT[f * 192 + j] = w_hh[i];
  } else if (idx < 32768) {
    int i = idx - 24576; int j = i >> 6, f = i & 63;
    w1T[f * 128 + j] = w1[i];
  } else if (idx < 40960) {
    int i = idx - 32768; int d = i >> 7, j = i & 127;
    w2T[j * 64 + d] = w2[i];
  } else if (idx < 45056) {
    int i = idx - 40960; int e = i >> 6, d = i & 63;
    wqT[d * 64 + e] = Wq[i];
  } else if (idx < 49152) {
    int i = idx - 45056; int d = i >> 6, f = i & 63;
    wvT[f * 64 + d] = Wv[i];         // wvT[f][d] = Wv[d][f]
  } else if (idx < 49344) {
    cnt[idx - 49152] = 0u;
  } else if (idx < 49408) {
    ready[idx - 49344] = 0u;
  }
}

// ---------------------------------------------------------------------------
// K2: persistent fused kernel: in-kernel LayerNorm + all 3 attention
// iterations + slot updates. R6 post-mortem: ~105us of the total was the
// ln_init dispatch + launch boundaries, while k_attn blocks already hold
// their xn chunk in registers — so xn never needs to exist in HBM at all.
//   - LN computed per-wave from inp (same lane map + shuffle order as the old
//     k_ln_init -> bit-identical), staged through the wave's LDS region into
//     kA registers. xn global buffer deleted (32MB write + 18MB read saved).
//   - Structure otherwise identical to R5 (kA-only persistent; per-iteration
//     vB transpose — R6's hoisted-vB variant spilled and regressed).
//   - RMW-free versioned protocol as R5/R6.
__global__ __launch_bounds__(256, 2) void k_attn(
    const float* __restrict__ inp,
    const float* __restrict__ g_in, const float* __restrict__ b_in,
    uintT* __restrict__ qU,
    float* __restrict__ accPart, float* __restrict__ colPart,
    uintT* __restrict__ cnt, uintT* __restrict__ ready,
    float* __restrict__ slotsV,
    const float* __restrict__ wihT, const float* __restrict__ whhT,
    const float* __restrict__ w1T, const float* __restrict__ w2T,
    const float* __restrict__ wqT, const float* __restrict__ Wk,
    const float* __restrict__ wvT,
    const float* __restrict__ b_ih, const float* __restrict__ b_hh,
    const float* __restrict__ mb1, const float* __restrict__ mb2,
    const float* __restrict__ g_ml, const float* __restrict__ b_ml,
    const float* __restrict__ g_sl, const float* __restrict__ b_sl,
    float* __restrict__ dout)
{
  __shared__ __align__(16) ushortT XW[4][4096];
  __shared__ int lastFlag;
  const int tid = threadIdx.x;
  const int lane = tid & 63;
  const int wave = tid >> 6;
  const int l15 = lane & 15, q = lane >> 4;
  const int b = blockIdx.x >> 3;
  const int e = blockIdx.x & 7;        // eighth of the batch

  ushortT* xT = &XW[wave][0];

  // ---- in-kernel LN: produce both chunks' A-frags straight into registers.
  // Same per-row lane mapping and reduction order as the old k_ln_init
  // (4 rows/pass, lane = (q=row-in-4, l15=col4)) -> bit-identical results.
  short8 kA0[4][2], kA1[4][2];
  {
    const float4 g4 = *(const float4*)&g_in[l15 << 2];
    const float4 b4 = *(const float4*)&b_in[l15 << 2];
#pragma unroll
    for (int ch = 0; ch < 2; ++ch) {
      const int chunk = (e << 3) + (ch << 2) + wave;   // 0..63
      const float* rowbase = inp + (((long)b * NN + (chunk << 6)) << 6);
#pragma unroll
      for (int pass = 0; pass < 16; ++pass) {
        const int row = (pass << 2) + q;
        float4 x = *(const float4*)&rowbase[(row << 6) + (l15 << 2)];
        float s = x.x + x.y + x.z + x.w;
        s += __shfl_xor(s, 1); s += __shfl_xor(s, 2);
        s += __shfl_xor(s, 4); s += __shfl_xor(s, 8);
        const float mu = s * (1.f / 64.f);
        float4 dx = {x.x - mu, x.y - mu, x.z - mu, x.w - mu};
        float ss = dx.x * dx.x + dx.y * dx.y + dx.z * dx.z + dx.w * dx.w;
        ss += __shfl_xor(ss, 1); ss += __shfl_xor(ss, 2);
        ss += __shfl_xor(ss, 4); ss += __shfl_xor(ss, 8);
        const float rs = rsqrtf(ss * (1.f / 64.f) + LN_EPS);
        us4 p = {f2bf(dx.x * rs * g4.x + b4.x), f2bf(dx.y * rs * g4.y + b4.y),
                 f2bf(dx.z * rs * g4.z + b4.z), f2bf(dx.w * rs * g4.w + b4.w)};
        // frag=(row>>4)*2+(l15>>3), lane'=((l15&7)>>1)*16+(row&15), j0=(l15&1)*4
        *(us4*)&xT[((((row >> 4) * 2 + (l15 >> 3)) << 6)
                    + (((l15 & 7) >> 1) << 4) + (row & 15)) * 8
                   + ((l15 & 1) << 2)] = p;
      }
      wait_lds();                        // all lanes' frag writes visible
#pragma unroll
      for (int mt = 0; mt < 4; ++mt)
#pragma unroll
        for (int kb = 0; kb < 2; ++kb) {
          short8 v = *(const short8*)&xT[((mt * 2 + kb) * 64 + lane) << 3];
          if (ch) kA1[mt][kb] = v; else kA0[mt][kb] = v;
        }
      wait_lds();                        // reads done before next overwrite
    }
  }

  for (int it = 0; it < 3; ++it) {
    if (it > 0) {
      if (tid == 0) {
        while (load1u_coh(&ready[b]) < (uintT)it) __builtin_amdgcn_s_sleep(2);
      }
      __syncthreads();
    }

    // q' for this iteration: versioned buffer -> first-touch plain loads
    const uintT* qIt = qU + it * 32768;
    short8 qB[2];
#pragma unroll
    for (int kb = 0; kb < 2; ++kb)
      qB[kb] = *(const short8*)&qIt[((b * 2 + kb) * 64 + lane) * 4];

    f32x4 accP[4];
#pragma unroll
    for (int nt = 0; nt < 4; ++nt) accP[nt] = (f32x4){0.f, 0.f, 0.f, 0.f};
    float csum = 0.f;

#pragma unroll
    for (int ch = 0; ch < 2; ++ch) {
      f32x4 accL[4];
#pragma unroll
      for (int mt = 0; mt < 4; ++mt) {
        const short8 a0 = ch ? kA1[mt][0] : kA0[mt][0];
        const short8 a1 = ch ? kA1[mt][1] : kA0[mt][1];
        accL[mt] = (f32x4){0.f, 0.f, 0.f, 0.f};
        accL[mt] = __builtin_amdgcn_mfma_f32_16x16x32_bf16(a0, qB[0], accL[mt], 0, 0, 0);
        accL[mt] = __builtin_amdgcn_mfma_f32_16x16x32_bf16(a1, qB[1], accL[mt], 0, 0, 0);
      }

      // in-LDS transpose: xn A-frags (j=f) -> PV B-frags (j=n), XOR-swizzled
      {
        const int h = ((lane >> 5) << 2) | (((lane & 15) >> 3) << 1) | ((lane >> 4) & 1);
        const int jp = lane & 7;
        const int lpA = (((lane >> 4) & 1) << 3) + (((lane & 15) >> 3) << 4);
#pragma unroll
        for (int mt = 0; mt < 4; ++mt)
#pragma unroll
          for (int kb = 0; kb < 2; ++kb) {
            const int fb = (kb * 4 + ((lane >> 5) << 1) + (mt >> 1)) << 9;
            const int lm = lpA + ((mt & 1) << 5);
            const short8 src8 = ch ? kA1[mt][kb] : kA0[mt][kb];
            const ushortT* src = (const ushortT*)&src8;
#pragma unroll
            for (int j = 0; j < 8; ++j)
              xT[fb + (((lm + j) ^ h) << 3) + jp] = src[j];
          }
      }
      short8 vB[4][2];
#pragma unroll
      for (int nt = 0; nt < 4; ++nt)
#pragma unroll
        for (int ks = 0; ks < 2; ++ks) {
          const int frag = nt * 2 + ks;
          const int hr = ((nt & 1) << 2) | (((lane >> 4) & 1) << 1) | ((lane >> 3) & 1);
          vB[nt][ks] = *(const short8*)&xT[(frag << 9) + ((lane ^ hr) << 3)];
        }

      // softmax over slots (cols 8..15 benign: q' cols zeroed)
      ushortT* attnF = &XW[wave][0];
#pragma unroll
      for (int mt = 0; mt < 4; ++mt) {
        float av[4];
#pragma unroll
        for (int r = 0; r < 4; ++r) {
          float lv = accL[mt][r];
          float mx = lv;
          mx = fmaxf(mx, __shfl_xor(mx, 1));
          mx = fmaxf(mx, __shfl_xor(mx, 2));
          mx = fmaxf(mx, __shfl_xor(mx, 4));
          float ev = __expf(lv - mx);
          float sv = ev;
          sv += __shfl_xor(sv, 1); sv += __shfl_xor(sv, 2); sv += __shfl_xor(sv, 4);
          float a = ev * (1.f / sv) + EPS;
          av[r] = a;
          csum += a;
        }
        us4 p = {f2bf(av[0]), f2bf(av[1]), f2bf(av[2]), f2bf(av[3])};
        *(us4*)&attnF[((((mt >> 1) << 6) + (((mt & 1) * 2 + (q >> 1)) << 4)
                        + l15) << 3) + ((q & 1) << 2)] = p;
      }

      short8 pA0 = *(const short8*)&attnF[(0 * 64 + lane) << 3];
      short8 pA1 = *(const short8*)&attnF[(1 * 64 + lane) << 3];

#pragma unroll
      for (int nt = 0; nt < 4; ++nt) {
        accP[nt] = __builtin_amdgcn_mfma_f32_16x16x32_bf16(pA0, vB[nt][0], accP[nt], 0, 0, 0);
        accP[nt] = __builtin_amdgcn_mfma_f32_16x16x32_bf16(pA1, vB[nt][1], accP[nt], 0, 0, 0);
      }
    }

    csum += __shfl_xor(csum, 16);
    csum += __shfl_xor(csum, 32);

    // cross-wave reduce in LDS, then one coherent store of the block partial
    float* accLw = (float*)&XW[wave][1024];
    float* colLw = (float*)&XW[wave][2048];
    if (q < 2) {
#pragma unroll
      for (int nt = 0; nt < 4; ++nt)
#pragma unroll
        for (int r = 0; r < 4; ++r)
          accLw[(q * 4 + r) * 64 + nt * 16 + l15] = accP[nt][r];
    }
    if (q == 0 && l15 < 8) colLw[l15] = csum;
    __syncthreads();

    float* apIt = accPart + ((long)(it * 64 + b) * 8 + e) * 512;
    float* cpIt = colPart + ((long)(it * 64 + b) * 8 + e) * 8;
    {
      const int o = tid * 2;
      f32x2 s;
#pragma unroll
      for (int r = 0; r < 2; ++r) {
        const int oo = o + r;
        s[r] = *((float*)&XW[0][1024] + oo) + *((float*)&XW[1][1024] + oo)
             + *((float*)&XW[2][1024] + oo) + *((float*)&XW[3][1024] + oo);
      }
      store2_coh(&apIt[o], s);
    }
    if (tid < 8) {
      float s = *((float*)&XW[0][2048] + tid) + *((float*)&XW[1][2048] + tid)
              + *((float*)&XW[2][2048] + tid) + *((float*)&XW[3][2048] + tid);
      store1f_coh(&cpIt[tid], s);
    }

    // completion: drain our stores, then last block of (it,b) runs the update
    drain_vm();
    __syncthreads();
    if (tid == 0) lastFlag = (atomicAdd(&cnt[it * 64 + b], 1u) == 7u);
    __syncthreads();

    if (lastFlag) {
      const int ks0 = wave, ks1 = wave + 4;
      const int row0 = b * 8 + ks0, row1 = b * 8 + ks1;
      const float* apB = accPart + (long)(it * 64 + b) * 8 * 512;
      const float* cpB = colPart + (long)(it * 64 + b) * 8 * 8;
      const float* slIt = slotsV + it * 32768;

      float csv0 = 0.f, csv1 = 0.f, t0 = 0.f, t1 = 0.f;
#pragma unroll
      for (int ee = 0; ee < 8; ++ee) {
        csv0 += cpB[ee * 8 + ks0];
        csv1 += cpB[ee * 8 + ks1];
        t0 += apB[ee * 512 + ks0 * 64 + lane];
        t1 += apB[ee * 512 + ks1 * 64 + lane];
      }
      t0 /= csv0; t1 /= csv1;
      const float h0 = slIt[row0 * 64 + lane];
      const float h1 = slIt[row1 * 64 + lane];

      float* S = (float*)&XW[wave][0];

      // updates = (t/csum) @ Wv^T  (f32 weights)
      S[256 + lane] = t0; S[320 + lane] = t1;
      float u0 = 0.f, u1 = 0.f;
#pragma unroll 4
      for (int f = 0; f < 64; ++f) {
        const float wv = wvT[f * 64 + lane];
        u0 = fmaf(S[256 + f], wv, u0);
        u1 = fmaf(S[320 + f], wv, u1);
      }

      S[lane] = u0; S[64 + lane] = u1; S[128 + lane] = h0; S[192 + lane] = h1;

      float gir0 = b_ih[lane], giz0 = b_ih[64 + lane], gin0 = b_ih[128 + lane];
      float ghr0 = b_hh[lane], ghz0 = b_hh[64 + lane], ghn0 = b_hh[128 + lane];
      float gir1 = gir0, giz1 = giz0, gin1 = gin0;
      float ghr1 = ghr0, ghz1 = ghz0, ghn1 = ghn0;
#pragma unroll 4
      for (int f = 0; f < 64; ++f) {
        const float wr = wihT[f * 192 + lane], wz = wihT[f * 192 + 64 + lane],
                    wn = wihT[f * 192 + 128 + lane];
        const float vr = whhT[f * 192 + lane], vz = whhT[f * 192 + 64 + lane],
                    vn = whhT[f * 192 + 128 + lane];
        const float a0 = S[f], a1 = S[64 + f], c0 = S[128 + f], c1 = S[192 + f];
        gir0 = fmaf(a0, wr, gir0); gir1 = fmaf(a1, wr, gir1);
        giz0 = fmaf(a0, wz, giz0); giz1 = fmaf(a1, wz, giz1);
        gin0 = fmaf(a0, wn, gin0); gin1 = fmaf(a1, wn, gin1);
        ghr0 = fmaf(c0, vr, ghr0); ghr1 = fmaf(c1, vr, ghr1);
        ghz0 = fmaf(c0, vz, ghz0); ghz1 = fmaf(c1, vz, ghz1);
        ghn0 = fmaf(c0, vn, ghn0); ghn1 = fmaf(c1, vn, ghn1);
      }
      const float r0 = 1.f / (1.f + expf(-(gir0 + ghr0)));
      const float z0 = 1.f / (1.f + expf(-(giz0 + ghz0)));
      const float n0 = tanhf(fmaf(r0, ghn0, gin0));
      const float hn0 = (1.f - z0) * n0 + z0 * h0;
      const float r1 = 1.f / (1.f + expf(-(gir1 + ghr1)));
      const float z1 = 1.f / (1.f + expf(-(giz1 + ghz1)));
      const float n1 = tanhf(fmaf(r1, ghn1, gin1));
      const float hn1 = (1.f - z1) * n1 + z1 * h1;

      float mu0 = wredsum(hn0) * (1.f / 64.f);
      float dx0 = hn0 - mu0;
      float va0 = wredsum(dx0 * dx0) * (1.f / 64.f);
      const float ln0 = dx0 * rsqrtf(va0 + LN_EPS) * g_ml[lane] + b_ml[lane];
      float mu1 = wredsum(hn1) * (1.f / 64.f);
      float dx1 = hn1 - mu1;
      float va1 = wredsum(dx1 * dx1) * (1.f / 64.f);
      const float ln1 = dx1 * rsqrtf(va1 + LN_EPS) * g_ml[lane] + b_ml[lane];
      S[256 + lane] = ln0; S[320 + lane] = ln1;

      float h1a0 = mb1[lane], h1b0 = mb1[64 + lane];
      float h1a1 = h1a0, h1b1 = h1b0;
#pragma unroll 4
      for (int f = 0; f < 64; ++f) {
        const float wa = w1T[f * 128 + lane], wb = w1T[f * 128 + 64 + lane];
        const float l0 = S[256 + f], l1 = S[320 + f];
        h1a0 = fmaf(l0, wa, h1a0); h1a1 = fmaf(l1, wa, h1a1);
        h1b0 = fmaf(l0, wb, h1b0); h1b1 = fmaf(l1, wb, h1b1);
      }
      h1a0 = fmaxf(h1a0, 0.f); h1b0 = fmaxf(h1b0, 0.f);
      h1a1 = fmaxf(h1a1, 0.f); h1b1 = fmaxf(h1b1, 0.f);
      S[lane] = h1a0; S[64 + lane] = h1b0;
      S[128 + lane] = h1a1; S[192 + lane] = h1b1;

      float o0 = mb2[lane], o1 = mb2[lane];
#pragma unroll 4
      for (int j = 0; j < 128; ++j) {
        const float w2v = w2T[j * 64 + lane];
        o0 = fmaf(S[j], w2v, o0);
        o1 = fmaf(S[128 + j], w2v, o1);
      }
      const float sn0 = hn0 + o0;
      const float sn1 = hn1 + o1;

      if (it == 2) {
        dout[row0 * 64 + lane] = sn0;
        dout[row1 * 64 + lane] = sn1;
      } else {
        // publish next-iteration slots (coherent stores, versioned buffer)
        float* slN = slotsV + (it + 1) * 32768;
        store1f_coh(&slN[row0 * 64 + lane], sn0);
        store1f_coh(&slN[row1 * 64 + lane], sn1);

        // next-iteration q' = (LN_slots(snew) @ Wq^T) @ Wk * D^-0.5
        float m20 = wredsum(sn0) * (1.f / 64.f);
        float d20 = sn0 - m20;
        float v20 = wredsum(d20 * d20) * (1.f / 64.f);
        const float sq0 = d20 * rsqrtf(v20 + LN_EPS) * g_sl[lane] + b_sl[lane];
        float m21 = wredsum(sn1) * (1.f / 64.f);
        float d21 = sn1 - m21;
        float v21 = wredsum(d21 * d21) * (1.f / 64.f);
        const float sq1 = d21 * rsqrtf(v21 + LN_EPS) * g_sl[lane] + b_sl[lane];
        S[256 + lane] = sq0; S[320 + lane] = sq1;
        float qe0 = 0.f, qe1 = 0.f;
#pragma unroll 8
        for (int d = 0; d < 64; ++d) {
          const float wq = wqT[d * 64 + lane];
          qe0 = fmaf(S[256 + d], wq, qe0);
          qe1 = fmaf(S[320 + d], wq, qe1);
        }
        S[256 + lane] = qe0; S[320 + lane] = qe1;
        float qp0 = 0.f, qp1 = 0.f;
#pragma unroll 8
        for (int e2 = 0; e2 < 64; ++e2) {
          const float wk = Wk[e2 * 64 + lane];
          qp0 = fmaf(S[256 + e2], wk, qp0);
          qp1 = fmaf(S[320 + e2], wk, qp1);
        }
        S[384 + lane] = qp0 * 0.125f;
        S[448 + lane] = qp1 * 0.125f;
        {
          uintT* qN = qU + (it + 1) * 32768;
          const int rr = lane >> 5, L5 = lane & 31;
          const int kb = L5 >> 4, lrow = (L5 >> 2) & 3, j2 = L5 & 3;
          const int fA = kb * 32 + lrow * 8 + 2 * j2;
          const int ksr = rr ? ks1 : ks0;
          uintT u = pack2bf(S[384 + rr * 64 + fA], S[384 + rr * 64 + fA + 1]);
          store1u_coh(&qN[((b * 2 + kb) * 64 + lrow * 16 + ksr) * 4 + j2], u);
        }
        // drain publish stores, barrier, then raise the flag: flag visibility
        // implies data visibility (stores are memory-side).
        drain_vm();
        __syncthreads();
        if (tid == 0) atomicAdd(&ready[b], 1u);
      }
    }
  }
}

// ---------------------------------------------------------------------------
extern "C" void kernel_launch(void* const* d_in, const int* in_sizes, int n_in,
                              void* d_out, int out_size, void* d_ws, size_t ws_size,
                              hipStream_t stream) {
  const float* inp   = (const float*)d_in[0];
  const float* noise = (const float*)d_in[1];
  const float* smu   = (const float*)d_in[2];
  const float* slsig = (const float*)d_in[3];
  const float* Wq    = (const float*)d_in[4];
  const float* Wk    = (const float*)d_in[5];
  const float* Wv    = (const float*)d_in[6];
  const float* w_ih  = (const float*)d_in[7];
  const float* w_hh  = (const float*)d_in[8];
  const float* b_ih  = (const float*)d_in[9];
  const float* b_hh  = (const float*)d_in[10];
  const float* w1    = (const float*)d_in[11];
  const float* b1    = (const float*)d_in[12];
  const float* w2    = (const float*)d_in[13];
  const float* b2    = (const float*)d_in[14];
  const float* g_in  = (const float*)d_in[15];
  const float* bi_in = (const float*)d_in[16];
  const float* g_sl  = (const float*)d_in[17];
  const float* bi_sl = (const float*)d_in[18];
  const float* g_ml  = (const float*)d_in[19];
  const float* bi_ml = (const float*)d_in[20];

  float* ws      = (float*)d_ws;
  uintT* qU      = (uintT*)(ws + OFF_QU);
  float* ap      = ws + OFF_AP;
  float* cp      = ws + OFF_CP;
  float* sl      = ws + OFF_SLOTS;
  float* wihT    = ws + OFF_WIHT;
  float* whhT    = ws + OFF_WHHT;
  float* w1T     = ws + OFF_W1T;
  float* w2T     = ws + OFF_W2T;
  float* wqT     = ws + OFF_WQT;
  float* wvT     = ws + OFF_WVT;
  uintT* cnt     = (uintT*)(ws + OFF_CNT);
  uintT* rdy     = (uintT*)(ws + OFF_RDY);

  k_prep<<<322, 256, 0, stream>>>(w_ih, w_hh, w1, w2, Wq, Wv, Wk,
                                  noise, smu, slsig, g_sl, bi_sl,
                                  wihT, whhT, w1T, w2T, wqT, wvT,
                                  sl, qU, cnt, rdy);
  k_attn<<<512, 256, 0, stream>>>(inp, g_in, bi_in, qU, ap, cp, cnt, rdy, sl,
                                  wihT, whhT, w1T, w2T, wqT, Wk, wvT,
                                  b_ih, b_hh, b1, b2, g_ml, bi_ml, g_sl, bi_sl,
                                  (float*)d_out);
}